// Round 6
// baseline (410.289 us; speedup 1.0000x reference)
//
#include <hip/hip_runtime.h>
#include <hip/hip_bf16.h>

// GAT layer, N=8192, D_IN=512, D_OUT=128.
// Identity: softmax row-max cancels a1[i]; attention_ij = adj_ij*e^{a2_j} / sum_j adj_ij*e^{a2_j}.
// Pipeline (ws = 2.4 MB):
//   k_cvtW: W[512][128] fp32 -> WT[2][128][512] bf16 hi/lo planes (transposed)
//   k_h   : x staged to LDS as hi/lo bf16 (swizzled); h = x@W via 3-term MFMA;
//           a2+exp fused; writes Gt[129][8192] bf16 (row 128 = e_j). grid 512.
//   k_gat : out = (adj @ G) / den. 3-buffer ring pipeline (T3+T4): B staged 2 tiles
//           ahead via global_load_lds, adj regs 2 ahead / converted 1 ahead,
//           counted s_waitcnt vmcnt(7) + raw s_barrier (no vmcnt(0) in loop).
//           den in VALU from adj regs. BM=32, BK=128, grid 256 x 512thr.

#define NN 8192
#define DIN 512
#define DOUT 128

typedef __attribute__((ext_vector_type(4))) int   int4v;
typedef __attribute__((ext_vector_type(4))) float f32x4;
typedef __attribute__((ext_vector_type(8))) short bf16x8;

static __device__ __forceinline__ unsigned short f2bf(float f) {
    unsigned u = __float_as_uint(f);
    return (unsigned short)((u + 0x7FFFu + ((u >> 16) & 1u)) >> 16);
}
static __device__ __forceinline__ float bf2f(unsigned short b) {
    return __uint_as_float((unsigned)b << 16);
}
static __device__ __forceinline__ void gload_lds16(const void* g, void* l) {
    __builtin_amdgcn_global_load_lds(
        (const __attribute__((address_space(1))) unsigned*)g,
        (__attribute__((address_space(3))) unsigned*)l, 16, 0, 0);
}
static __device__ __forceinline__ int4v ntld(const int* p) {
    return __builtin_nontemporal_load(reinterpret_cast<const int4v*>(p));
}
static __device__ __forceinline__ f32x4 ntldf4(const float* p) {
    return __builtin_nontemporal_load(reinterpret_cast<const f32x4*>(p));
}

// ---------------- k_cvtW: W -> WT[2][128][512] bf16 (hi, lo residual) ----------------
__global__ __launch_bounds__(256) void k_cvtW(const float* __restrict__ W,
                                              unsigned short* __restrict__ WT) {
    __shared__ float s[8][128];
    const int t  = threadIdx.x;
    const int k0 = blockIdx.x * 8;      // grid 64
    {
        int idx = t * 4;
        int k = idx >> 7, d = idx & 127;
        float4 v = *reinterpret_cast<const float4*>(&W[(size_t)(k0 + k) * DOUT + d]);
        *reinterpret_cast<float4*>(&s[k][d]) = v;
    }
    __syncthreads();
    const int d  = t & 127;
    const int pl = t >> 7;              // 0 = hi, 1 = lo
    unsigned short o[8];
    #pragma unroll
    for (int kk = 0; kk < 8; ++kk) {
        float f = s[kk][d];
        unsigned short hb = f2bf(f);
        o[kk] = pl ? f2bf(f - bf2f(hb)) : hb;
    }
    *reinterpret_cast<uint4*>(&WT[(size_t)pl * 128 * DIN + (size_t)d * DIN + k0]) =
        *reinterpret_cast<const uint4*>(o);
}

// ---------------- k_h: h-GEMM + a2 + Gt build ----------------
// grid 512, 256 thr (4 waves). Wave w: cols w*32..+31 (2 ct), rows j0..j0+15.
__global__ __launch_bounds__(256) void k_h(const float* __restrict__ x,
                                           const unsigned short* __restrict__ WT,
                                           const float* __restrict__ wa2,
                                           unsigned short* __restrict__ Gt) {
    __shared__ __align__(16) char xs[32768];   // [2 planes][16 rows][512 bf16], swizzled
    __shared__ float red[4][16];
    __shared__ float es[16];
    const int t = threadIdx.x;
    const int w = t >> 6, l = t & 63;
    const int c = l & 15, g = l >> 4;
    const int j0 = blockIdx.x * 16;

    // ---- stage x: 8 float4/thread -> hi/lo bf16 swizzled LDS ----
    f32x4 xv[8];
    #pragma unroll
    for (int s = 0; s < 8; ++s) {
        int ii = t + s * 256;
        int r = ii >> 7, k4 = ii & 127;
        xv[s] = ntldf4(&x[(size_t)(j0 + r) * DIN + k4 * 4]);
    }
    #pragma unroll
    for (int s = 0; s < 8; ++s) {
        int ii = t + s * 256;
        int r = ii >> 7, k4 = ii & 127;
        unsigned byte0 = (unsigned)r * 1024 +
                         ((((unsigned)(k4 >> 1)) ^ ((unsigned)(r & 15))) << 4) + (k4 & 1) * 8;
        float vf[4] = {xv[s].x, xv[s].y, xv[s].z, xv[s].w};
        unsigned short hb[4], lb[4];
        #pragma unroll
        for (int e = 0; e < 4; ++e) { hb[e] = f2bf(vf[e]); lb[e] = f2bf(vf[e] - bf2f(hb[e])); }
        uint2 hv = {(unsigned)hb[0] | ((unsigned)hb[1] << 16),
                    (unsigned)hb[2] | ((unsigned)hb[3] << 16)};
        uint2 lv = {(unsigned)lb[0] | ((unsigned)lb[1] << 16),
                    (unsigned)lb[2] | ((unsigned)lb[3] << 16)};
        *reinterpret_cast<uint2*>(xs + byte0) = hv;
        *reinterpret_cast<uint2*>(xs + 16384 + byte0) = lv;
    }
    __syncthreads();

    // ---- GEMM with 2-deep register pipeline on WT (L2) ----
    const int wc0 = w * 32;
    const unsigned short* pB00 = WT + (size_t)(wc0 + c) * DIN + g * 8;   // ct0 hi
    const unsigned short* pB01 = pB00 + 16 * DIN;                        // ct1 hi
    const unsigned short* pB10 = pB00 + 128 * DIN;                       // ct0 lo
    const unsigned short* pB11 = pB01 + 128 * DIN;                       // ct1 lo

    f32x4 acc0 = (f32x4)0.f, acc1 = (f32x4)0.f;
    const unsigned arow = (unsigned)c * 1024;
    const unsigned aswz = (unsigned)(c & 15);

    bf16x8 e00 = *reinterpret_cast<const bf16x8*>(pB00);
    bf16x8 e01 = *reinterpret_cast<const bf16x8*>(pB01);
    bf16x8 e10 = *reinterpret_cast<const bf16x8*>(pB10);
    bf16x8 e11 = *reinterpret_cast<const bf16x8*>(pB11);
    bf16x8 o00 = *reinterpret_cast<const bf16x8*>(pB00 + 32);
    bf16x8 o01 = *reinterpret_cast<const bf16x8*>(pB01 + 32);
    bf16x8 o10 = *reinterpret_cast<const bf16x8*>(pB10 + 32);
    bf16x8 o11 = *reinterpret_cast<const bf16x8*>(pB11 + 32);

    #pragma unroll
    for (int ks = 0; ks < 16; ks += 2) {
        {   // kstep ks (even set)
            unsigned ab = arow + ((((unsigned)(ks * 4 + g)) ^ aswz) << 4);
            bf16x8 ahi = *reinterpret_cast<const bf16x8*>(xs + ab);
            bf16x8 alo = *reinterpret_cast<const bf16x8*>(xs + 16384 + ab);
            acc0 = __builtin_amdgcn_mfma_f32_16x16x32_bf16(ahi, e00, acc0, 0, 0, 0);
            acc1 = __builtin_amdgcn_mfma_f32_16x16x32_bf16(ahi, e01, acc1, 0, 0, 0);
            acc0 = __builtin_amdgcn_mfma_f32_16x16x32_bf16(ahi, e10, acc0, 0, 0, 0);
            acc1 = __builtin_amdgcn_mfma_f32_16x16x32_bf16(ahi, e11, acc1, 0, 0, 0);
            acc0 = __builtin_amdgcn_mfma_f32_16x16x32_bf16(alo, e00, acc0, 0, 0, 0);
            acc1 = __builtin_amdgcn_mfma_f32_16x16x32_bf16(alo, e01, acc1, 0, 0, 0);
            if (ks + 2 < 16) {
                e00 = *reinterpret_cast<const bf16x8*>(pB00 + (ks + 2) * 32);
                e01 = *reinterpret_cast<const bf16x8*>(pB01 + (ks + 2) * 32);
                e10 = *reinterpret_cast<const bf16x8*>(pB10 + (ks + 2) * 32);
                e11 = *reinterpret_cast<const bf16x8*>(pB11 + (ks + 2) * 32);
            }
        }
        {   // kstep ks+1 (odd set)
            unsigned ab = arow + ((((unsigned)((ks + 1) * 4 + g)) ^ aswz) << 4);
            bf16x8 ahi = *reinterpret_cast<const bf16x8*>(xs + ab);
            bf16x8 alo = *reinterpret_cast<const bf16x8*>(xs + 16384 + ab);
            acc0 = __builtin_amdgcn_mfma_f32_16x16x32_bf16(ahi, o00, acc0, 0, 0, 0);
            acc1 = __builtin_amdgcn_mfma_f32_16x16x32_bf16(ahi, o01, acc1, 0, 0, 0);
            acc0 = __builtin_amdgcn_mfma_f32_16x16x32_bf16(ahi, o10, acc0, 0, 0, 0);
            acc1 = __builtin_amdgcn_mfma_f32_16x16x32_bf16(ahi, o11, acc1, 0, 0, 0);
            acc0 = __builtin_amdgcn_mfma_f32_16x16x32_bf16(alo, o00, acc0, 0, 0, 0);
            acc1 = __builtin_amdgcn_mfma_f32_16x16x32_bf16(alo, o01, acc1, 0, 0, 0);
            if (ks + 3 < 16) {
                o00 = *reinterpret_cast<const bf16x8*>(pB00 + (ks + 3) * 32);
                o01 = *reinterpret_cast<const bf16x8*>(pB01 + (ks + 3) * 32);
                o10 = *reinterpret_cast<const bf16x8*>(pB10 + (ks + 3) * 32);
                o11 = *reinterpret_cast<const bf16x8*>(pB11 + (ks + 3) * 32);
            }
        }
    }

    // ---- a2 reduce + exp ----
    const float wl0 = wa2[wc0 + c];
    const float wl1 = wa2[wc0 + 16 + c];
    #pragma unroll
    for (int r = 0; r < 4; ++r) {
        float p = acc0[r] * wl0 + acc1[r] * wl1;
        p += __shfl_xor(p, 1); p += __shfl_xor(p, 2);
        p += __shfl_xor(p, 4); p += __shfl_xor(p, 8);
        if (c == 0) red[w][g * 4 + r] = p;
    }
    __syncthreads();
    if (t < 16) es[t] = expf(red[0][t] + red[1][t] + red[2][t] + red[3][t]);
    __syncthreads();

    {   // Gt cols wc0+c (ct0) and wc0+16+c (ct1), rows j0+g*4..+3
        unsigned short b0[4], b1[4];
        #pragma unroll
        for (int r = 0; r < 4; ++r) {
            b0[r] = f2bf(acc0[r] * es[g * 4 + r]);
            b1[r] = f2bf(acc1[r] * es[g * 4 + r]);
        }
        uint2 v0 = {(unsigned)b0[0] | ((unsigned)b0[1] << 16),
                    (unsigned)b0[2] | ((unsigned)b0[3] << 16)};
        uint2 v1 = {(unsigned)b1[0] | ((unsigned)b1[1] << 16),
                    (unsigned)b1[2] | ((unsigned)b1[3] << 16)};
        *reinterpret_cast<uint2*>(&Gt[(size_t)(wc0 + c) * NN + j0 + g * 4]) = v0;
        *reinterpret_cast<uint2*>(&Gt[(size_t)(wc0 + 16 + c) * NN + j0 + g * 4]) = v1;
    }
    if (t < 8) {   // row 128 = e_j
        unsigned u = (unsigned)f2bf(es[t * 2]) | ((unsigned)f2bf(es[t * 2 + 1]) << 16);
        reinterpret_cast<unsigned*>(&Gt[(size_t)128 * NN + j0])[t] = u;
    }
}

// ---------------- k_gat: out = (adj @ G) / den, 3-ring counted-vmcnt pipeline ----------------
__global__ __launch_bounds__(512) void k_gat(const int* __restrict__ adj,
                                             const unsigned short* __restrict__ Gt,
                                             float* __restrict__ out) {
    // ABUF i @ i*8192 (32x256B bf16 swz); BBUF i @ 24576+i*32768 (128x256B bf16 swz)
    // denp @122880 f32[32][32]; den_l @126976 f32[32]
    __shared__ __align__(16) char lds[127104];
    float* denp  = (float*)(lds + 122880);
    float* den_l = (float*)(lds + 126976);
    const int t = threadIdx.x;
    const int w = t >> 6, l = t & 63;
    const int c = l & 15, g = l >> 4;
    const int wm = w >> 2, wc = w & 3;
    const int row0 = blockIdx.x * 32;   // grid 256

    f32x4 acc0 = (f32x4)0.f, acc1 = (f32x4)0.f;
    float d0 = 0.f, d1 = 0.f;

    // A staging: thread owns rows r0 and r0+16, k-granule kg (4 ints)
    const int r0 = t >> 5;
    const int kg = t & 31;
    const int* ap0 = adj + (size_t)(row0 + r0) * NN + kg * 4;
    const int* ap1 = ap0 + (size_t)16 * NN;
    const unsigned short* ep = Gt + (size_t)128 * NN + kg * 4;
    const unsigned aw0 = (unsigned)r0 * 256 + (((unsigned)(kg * 8)) ^ (((unsigned)(r0 & 15)) << 4));
    const unsigned aw1 = aw0 + 4096;

    // fragment-read constants
    const unsigned abase = ((unsigned)(wm * 16 + c)) * 256;
    const unsigned afswz = ((unsigned)c) << 4;
    const unsigned br0 = (unsigned)(wc * 32 + c);
    const unsigned br1 = br0 + 16;
    const unsigned b0base = br0 * 256, b0swz = (br0 & 15) << 4;
    const unsigned b1base = br1 * 256, b1swz = (br1 & 15) << 4;

#define ISSUE_B(boff, ko) { char* Bn_ = lds + 24576 + (boff); \
    _Pragma("unroll") for (int s_ = 0; s_ < 4; ++s_) { \
        int ii_ = t + s_ * 512; int rb_ = ii_ >> 4, pb_ = ii_ & 15; \
        int gk_ = pb_ ^ (rb_ & 15); \
        gload_lds16(Gt + (size_t)rb_ * NN + (ko) + gk_ * 8, Bn_ + ii_ * 16); } }

#define LOAD_A(A0, A1, EV, ko) { A0 = ntld(ap0 + (ko)); A1 = ntld(ap1 + (ko)); \
    EV = *reinterpret_cast<const uint2*>(ep + (ko)); }

#define CONV_A(A0, A1, EV, aoff) { char* An_ = lds + (aoff); \
    unsigned u00_ = ((unsigned)A0.x | ((unsigned)A0.y << 16)) * 0x3F80u; \
    unsigned u01_ = ((unsigned)A0.z | ((unsigned)A0.w << 16)) * 0x3F80u; \
    unsigned u10_ = ((unsigned)A1.x | ((unsigned)A1.y << 16)) * 0x3F80u; \
    unsigned u11_ = ((unsigned)A1.z | ((unsigned)A1.w << 16)) * 0x3F80u; \
    uint2 w0_ = {u00_, u01_}, w1_ = {u10_, u11_}; \
    *reinterpret_cast<uint2*>(An_ + aw0) = w0_; \
    *reinterpret_cast<uint2*>(An_ + aw1) = w1_; \
    float e0_ = bf2f((unsigned short)(EV.x & 0xFFFFu)); \
    float e1_ = bf2f((unsigned short)(EV.x >> 16)); \
    float e2_ = bf2f((unsigned short)(EV.y & 0xFFFFu)); \
    float e3_ = bf2f((unsigned short)(EV.y >> 16)); \
    d0 += (A0.x ? e0_ : 0.f) + (A0.y ? e1_ : 0.f) + (A0.z ? e2_ : 0.f) + (A0.w ? e3_ : 0.f); \
    d1 += (A1.x ? e0_ : 0.f) + (A1.y ? e1_ : 0.f) + (A1.z ? e2_ : 0.f) + (A1.w ? e3_ : 0.f); }

#define COMPUTE(idx) { const char* Ab_ = lds + (idx) * 8192; \
    const char* Bb_ = lds + 24576 + (idx) * 32768; \
    _Pragma("unroll") for (int ks_ = 0; ks_ < 4; ++ks_) { \
        unsigned ko_ = (unsigned)(ks_ * 64 + g * 16); \
        bf16x8 av_ = *reinterpret_cast<const bf16x8*>(Ab_ + abase + (ko_ ^ afswz)); \
        bf16x8 b0_ = *reinterpret_cast<const bf16x8*>(Bb_ + b0base + (ko_ ^ b0swz)); \
        bf16x8 b1_ = *reinterpret_cast<const bf16x8*>(Bb_ + b1base + (ko_ ^ b1swz)); \
        acc0 = __builtin_amdgcn_mfma_f32_16x16x32_bf16(av_, b0_, acc0, 0, 0, 0); \
        acc1 = __builtin_amdgcn_mfma_f32_16x16x32_bf16(av_, b1_, acc1, 0, 0, 0); } }

#define SYNC7() { asm volatile("s_waitcnt vmcnt(7) lgkmcnt(0)" ::: "memory"); \
    __builtin_amdgcn_sched_barrier(0); __builtin_amdgcn_s_barrier(); \
    __builtin_amdgcn_sched_barrier(0); }
#define SYNC0() { asm volatile("s_waitcnt vmcnt(0) lgkmcnt(0)" ::: "memory"); \
    __builtin_amdgcn_sched_barrier(0); __builtin_amdgcn_s_barrier(); \
    __builtin_amdgcn_sched_barrier(0); }

    int4v eA0, eA1; uint2 eEv;
    int4v oA0, oA1; uint2 oEv;

    // prologue: tiles 0,1 staged; A0 converted
    ISSUE_B(0, 0);
    LOAD_A(eA0, eA1, eEv, 0);
    ISSUE_B(32768, 128);
    LOAD_A(oA0, oA1, oEv, 128);
    CONV_A(eA0, eA1, eEv, 0);
    SYNC7();

    int i0 = 0, i1 = 1, i2 = 2;
    for (int kt = 0; kt < 62; kt += 2) {
        // process kt; prefetch kt+2 (E); convert tile kt+1 (O)
        ISSUE_B(i2 * 32768, (kt + 2) * 128);
        LOAD_A(eA0, eA1, eEv, (kt + 2) * 128);
        COMPUTE(i0);
        CONV_A(oA0, oA1, oEv, i1 * 8192);
        SYNC7();
        { int tmp_ = i0; i0 = i1; i1 = i2; i2 = tmp_; }
        // process kt+1; prefetch kt+3 (O); convert tile kt+2 (E)
        ISSUE_B(i2 * 32768, (kt + 3) * 128);
        LOAD_A(oA0, oA1, oEv, (kt + 3) * 128);
        COMPUTE(i0);
        CONV_A(eA0, eA1, eEv, i1 * 8192);
        SYNC7();
        { int tmp_ = i0; i0 = i1; i1 = i2; i2 = tmp_; }
    }
    // kt = 62: nothing left to prefetch; convert tile 63 (O); full drain
    COMPUTE(i0);
    CONV_A(oA0, oA1, oEv, i1 * 8192);
    SYNC0();
    { int tmp_ = i0; i0 = i1; i1 = i2; i2 = tmp_; }
    // kt = 63
    COMPUTE(i0);

#undef ISSUE_B
#undef LOAD_A
#undef CONV_A
#undef COMPUTE
#undef SYNC7
#undef SYNC0

    // ---- den reduce + epilogue ----
    denp[r0 * 32 + kg] = d0;
    denp[(16 + r0) * 32 + kg] = d1;
    __syncthreads();
    if (t < 32) {
        float s = 0.f;
        #pragma unroll
        for (int q = 0; q < 32; ++q) s += denp[t * 32 + q];
        den_l[t] = s;
    }
    __syncthreads();

    #pragma unroll
    for (int r = 0; r < 4; ++r) {
        float inv = 1.0f / den_l[wm * 16 + g * 4 + r];
        float* orow = out + (size_t)(row0 + wm * 16 + g * 4 + r) * DOUT + wc * 32 + c;
        orow[0]  = acc0[r] * inv;
        orow[16] = acc1[r] * inv;
    }
}

extern "C" void kernel_launch(void* const* d_in, const int* in_sizes, int n_in,
                              void* d_out, int out_size, void* d_ws, size_t ws_size,
                              hipStream_t stream) {
    const float* x   = (const float*)d_in[0];
    const int*   adj = (const int*)d_in[1];
    const float* W   = (const float*)d_in[2];
    // d_in[3] = w_a1: unused — cancels in row softmax.
    const float* wa2 = (const float*)d_in[4];
    float* out = (float*)d_out;

    char* ws = (char*)d_ws;
    unsigned short* WT = (unsigned short*)ws;                   // 256 KB
    unsigned short* Gt = (unsigned short*)(ws + 262144);        // 129*8192*2 = 2.064 MB

    k_cvtW<<< 64, 256, 0, stream>>>(W, WT);
    k_h   <<<512, 256, 0, stream>>>(x, WT, wa2, Gt);
    k_gat <<<256, 512, 0, stream>>>(adj, Gt, out);
}